// Round 2
// baseline (503.145 us; speedup 1.0000x reference)
//
#include <hip/hip_runtime.h>
#include <stdint.h>

typedef unsigned short u16;
typedef __attribute__((ext_vector_type(8))) short short8;
typedef __attribute__((ext_vector_type(4))) float f32x4;

__device__ __forceinline__ u16 f2bf(float f) {
  uint32_t x = __float_as_uint(f);
  x += 0x7fff + ((x >> 16) & 1);
  return (u16)(x >> 16);
}
__device__ __forceinline__ float bf2f(u16 u) {
  return __uint_as_float(((uint32_t)u) << 16);
}
__device__ __forceinline__ f32x4 mfma16(short8 a, short8 b, f32x4 c) {
  return __builtin_amdgcn_mfma_f32_16x16x32_bf16(a, b, c, 0, 0, 0);
}
__device__ __forceinline__ void gld16(const u16* g, u16* l) {
  __builtin_amdgcn_global_load_lds(
      (const __attribute__((address_space(1))) unsigned int*)g,
      (__attribute__((address_space(3))) unsigned int*)l, 16, 0, 0);
}

// ---------------- fp32 -> bf16 conversion ----------------
__global__ __launch_bounds__(256) void cvt_bf16(const float* __restrict__ s,
                                                u16* __restrict__ d, int n) {
  int i = (blockIdx.x * 256 + threadIdx.x) * 8;
  if (i >= n) return;
  f32x4 a = *(const f32x4*)(s + i);
  f32x4 b = *(const f32x4*)(s + i + 4);
  short8 o;
#pragma unroll
  for (int j = 0; j < 4; j++) {
    o[j] = (short)f2bf(a[j]);
    o[j + 4] = (short)f2bf(b[j]);
  }
  *(short8*)(d + i) = o;
}

// ---------------- m97-style BT GEMM: C = A(MxK) * B(NxK)^T ----------------
// EPI=0: scatter bf16 into q/k/v head-major [3][B=2][H=16][T=2048][128]
// EPI=1: fp32 row-major MxN
template <int EPI>
__global__ __launch_bounds__(256) void gemm_bt(const u16* __restrict__ A,
                                               const u16* __restrict__ B,
                                               int K, void* __restrict__ Cv, int N) {
  __shared__ __align__(16) u16 As[4096];  // 128 x 32
  __shared__ __align__(16) u16 Bs[4096];  // 128 x 32
  const int m0 = blockIdx.y * 128, n0 = blockIdx.x * 128;
  const int t = threadIdx.x, w = t >> 6, lane = t & 63;
  const int quad = lane >> 4, l15 = lane & 15;
  const int rb = (w >> 1) * 64, cb = (w & 1) * 64;
  f32x4 acc[4][4] = {};
  const u16* ag = A + (size_t)(m0 + w * 16 + (lane >> 2)) * K + (lane & 3) * 8;
  const u16* bg = B + (size_t)(n0 + w * 16 + (lane >> 2)) * K + (lane & 3) * 8;
  u16* al = As + w * 512 + lane * 8;  // lane-contiguous: base + lane*16B
  u16* bl = Bs + w * 512 + lane * 8;
  const size_t rowskip = (size_t)64 * K;
  for (int k0 = 0; k0 < K; k0 += 32) {
    __syncthreads();
    gld16(ag, al);
    gld16(ag + rowskip, al + 2048);
    gld16(bg, bl);
    gld16(bg + rowskip, bl + 2048);
    ag += 32;
    bg += 32;
    __syncthreads();
    short8 af[4], bfr[4];
#pragma unroll
    for (int mf = 0; mf < 4; mf++)
      af[mf] = *(const short8*)&As[(rb + mf * 16 + l15) * 32 + quad * 8];
#pragma unroll
    for (int nf = 0; nf < 4; nf++)
      bfr[nf] = *(const short8*)&Bs[(cb + nf * 16 + l15) * 32 + quad * 8];
#pragma unroll
    for (int mf = 0; mf < 4; mf++)
#pragma unroll
      for (int nf = 0; nf < 4; nf++)
        acc[mf][nf] = mfma16(af[mf], bfr[nf], acc[mf][nf]);
  }
  if (EPI == 0) {
    u16* q3 = (u16*)Cv;
#pragma unroll
    for (int mf = 0; mf < 4; mf++)
#pragma unroll
      for (int nf = 0; nf < 4; nf++)
#pragma unroll
        for (int rg = 0; rg < 4; rg++) {
          int m = m0 + rb + mf * 16 + quad * 4 + rg;
          int n = n0 + cb + nf * 16 + l15;
          int which = n >> 11, dd = n & 2047;
          int hh = dd >> 7, di = dd & 127;
          int bb = m >> 11, tt = m & 2047;
          q3[(size_t)which * 8388608 +
             ((size_t)((bb * 16 + hh) * 2048 + tt)) * 128 + di] =
              f2bf(acc[mf][nf][rg]);
        }
  } else {
    float* C = (float*)Cv;
#pragma unroll
    for (int mf = 0; mf < 4; mf++)
#pragma unroll
      for (int nf = 0; nf < 4; nf++)
#pragma unroll
        for (int rg = 0; rg < 4; rg++) {
          int m = m0 + rb + mf * 16 + quad * 4 + rg;
          int n = n0 + cb + nf * 16 + l15;
          C[(size_t)m * N + n] = acc[mf][nf][rg];
        }
  }
}

// ---------------- RoPE in-place on q,k (heads 0..7 only) ----------------
__global__ __launch_bounds__(256) void rope_k(u16* __restrict__ q, u16* __restrict__ k,
                                              const float* __restrict__ cosT,
                                              const float* __restrict__ sinT) {
  int t = threadIdx.x;
  int row = blockIdx.x * 4 + (t >> 6);  // over (b, h<8, tpos)
  int i = t & 63;
  int b = row >> 14;
  int h = (row >> 11) & 7;
  int tp = row & 2047;
  size_t base = ((size_t)((b * 16 + h) * 2048 + tp)) * 128 + 2 * i;
  float c = cosT[tp * 64 + i], s = sinT[tp * 64 + i];
  {
    uint32_t u = *(uint32_t*)(q + base);
    float x0 = bf2f((u16)(u & 0xffff)), x1 = bf2f((u16)(u >> 16));
    float re = x0 * c - x1 * s, im = x0 * s + x1 * c;
    *(uint32_t*)(q + base) = (uint32_t)f2bf(re) | ((uint32_t)f2bf(im) << 16);
  }
  {
    uint32_t u = *(uint32_t*)(k + base);
    float x0 = bf2f((u16)(u & 0xffff)), x1 = bf2f((u16)(u >> 16));
    float re = x0 * c - x1 * s, im = x0 * s + x1 * c;
    *(uint32_t*)(k + base) = (uint32_t)f2bf(re) | ((uint32_t)f2bf(im) << 16);
  }
}

// ---------------- per-head V transpose: [bh][t][d] -> [bh][d][t] ----------------
__global__ __launch_bounds__(256) void transpose_v(const u16* __restrict__ v,
                                                   u16* __restrict__ vT) {
  int t0 = blockIdx.x * 64, d0 = blockIdx.y * 64, bh = blockIdx.z;
  __shared__ __align__(16) u16 tile[64 * 72];
  int t = threadIdx.x;
#pragma unroll
  for (int i = 0; i < 2; i++) {
    int c = t + i * 256;
    int r = c >> 3, c8 = c & 7;
    short8 val = *(const short8*)(v + ((size_t)(bh * 2048 + t0 + r)) * 128 + d0 + c8 * 8);
    *(short8*)&tile[r * 72 + c8 * 8] = val;
  }
  __syncthreads();
#pragma unroll
  for (int i = 0; i < 2; i++) {
    int c = t + i * 256;
    int d = c >> 3, t8 = c & 7;
    short8 o;
#pragma unroll
    for (int j = 0; j < 8; j++) o[j] = (short)tile[(t8 * 8 + j) * 72 + d];
    *(short8*)(vT + ((size_t)(bh * 128 + d0 + d)) * 2048 + t0 + t8 * 8) = o;
  }
}

// ---------------- flash attention: Q-tile 64, K-tile 64, hd=128 ----------------
__global__ __launch_bounds__(256) void attn_k(const u16* __restrict__ qh,
                                              const u16* __restrict__ kh,
                                              const u16* __restrict__ vTh,
                                              u16* __restrict__ attno) {
  const int qt = blockIdx.x, bh = blockIdx.y;
  const int q0 = qt * 64;
  const int t = threadIdx.x, w = t >> 6, lane = t & 63;
  const int quad = lane >> 4, l15 = lane & 15;
  __shared__ __align__(16) u16 Kls[64 * 136];
  __shared__ __align__(16) u16 Vt[128 * 72];
  __shared__ __align__(16) float SP[64 * 68];  // S fp32 (pitch 68); P bf16 aliased (u16 pitch 136)
  __shared__ float pmaxL[256], psumL[256], alphaL[64], mstate[64], lstate[64];
  const float SCALE = 0.08838834764831845f;  // 1/sqrt(128)
  const float NINF = __uint_as_float(0xff800000u);

  short8 qa[4];
  {
    const u16* qp = qh + ((size_t)(bh * 2048 + q0 + w * 16 + l15)) * 128 + quad * 8;
#pragma unroll
    for (int ks = 0; ks < 4; ks++) qa[ks] = *(const short8*)(qp + ks * 32);
  }
  f32x4 of[8] = {};
  if (t < 64) {
    mstate[t] = NINF;
    lstate[t] = 0.f;
  }
  const int r = t >> 2, c0g = (t & 3) * 16, g = t & 3;
  const int ntiles = qt + 1;
  for (int kt = 0; kt < ntiles; kt++) {
    const int k0 = kt * 64;
    __syncthreads();  // A: protect LDS from overwrite
    {
      const u16* kbase = kh + ((size_t)(bh * 2048 + k0)) * 128;
#pragma unroll
      for (int i2 = 0; i2 < 4; i2++) {
        int c = t + i2 * 256;  // 64 rows x 16 chunks
        int key = c >> 4, c16 = c & 15;
        short8 v = *(const short8*)(kbase + (size_t)key * 128 + c16 * 8);
        *(short8*)&Kls[key * 136 + c16 * 8] = v;
      }
      const u16* vbase = vTh + (size_t)bh * 128 * 2048 + k0;
#pragma unroll
      for (int i2 = 0; i2 < 4; i2++) {
        int c = t + i2 * 256;  // 128 rows x 8 chunks
        int d = c >> 3, c8 = c & 7;
        short8 v = *(const short8*)(vbase + (size_t)d * 2048 + c8 * 8);
        *(short8*)&Vt[d * 72 + c8 * 8] = v;
      }
    }
    __syncthreads();  // B: staging visible
    // S = Q * K^T (scaled)
    {
      f32x4 sacc[4] = {};
#pragma unroll
      for (int ks = 0; ks < 4; ks++) {
        short8 kb[4];
#pragma unroll
        for (int nf = 0; nf < 4; nf++)
          kb[nf] = *(const short8*)&Kls[(nf * 16 + l15) * 136 + ks * 32 + quad * 8];
#pragma unroll
        for (int nf = 0; nf < 4; nf++) sacc[nf] = mfma16(qa[ks], kb[nf], sacc[nf]);
      }
#pragma unroll
      for (int nf = 0; nf < 4; nf++)
#pragma unroll
        for (int rg = 0; rg < 4; rg++)
          SP[(w * 16 + quad * 4 + rg) * 68 + nf * 16 + l15] = sacc[nf][rg] * SCALE;
    }
    __syncthreads();  // C: S visible
    // pass1: read 16 cols, mask, partial max
    float sv[16];
    {
      const f32x4* sp = (const f32x4*)&SP[r * 68 + c0g];
      f32x4 s4[4];
#pragma unroll
      for (int jj = 0; jj < 4; jj++) s4[jj] = sp[jj];
#pragma unroll
      for (int j = 0; j < 16; j++) sv[j] = s4[j >> 2][j & 3];
    }
    float mold = mstate[r];
    const bool diag = (kt == qt);
    float pm = NINF;
#pragma unroll
    for (int j = 0; j < 16; j++) {
      if (diag && (c0g + j > r)) sv[j] = NINF;
      pm = fmaxf(pm, sv[j]);
    }
    pmaxL[t] = pm;
    __syncthreads();  // D: pmax visible
    float mrow = fmaxf(fmaxf(pmaxL[r * 4], pmaxL[r * 4 + 1]),
                       fmaxf(pmaxL[r * 4 + 2], pmaxL[r * 4 + 3]));
    float mnew = fmaxf(mold, mrow);
    float alpha = __expf(mold - mnew);
    float e[16];
    float ps = 0.f;
#pragma unroll
    for (int j = 0; j < 16; j++) {
      e[j] = __expf(sv[j] - mnew);
      ps += e[j];
    }
    {  // write P bf16 over S region (same row, cols already consumed by this wave)
      u16* pp = (u16*)SP + r * 136 + c0g;
      short8 p0, p1;
#pragma unroll
      for (int j = 0; j < 8; j++) {
        p0[j] = (short)f2bf(e[j]);
        p1[j] = (short)f2bf(e[j + 8]);
      }
      *(short8*)pp = p0;
      *(short8*)(pp + 8) = p1;
    }
    psumL[t] = ps;
    if (g == 0) alphaL[r] = alpha;
    __syncthreads();  // E: P, psum, alpha visible
    if (g == 0) {
      lstate[r] = lstate[r] * alpha +
                  psumL[r * 4] + psumL[r * 4 + 1] + psumL[r * 4 + 2] + psumL[r * 4 + 3];
      mstate[r] = mnew;
    }
    // rescale O and accumulate P*V
    float ar[4];
#pragma unroll
    for (int rg = 0; rg < 4; rg++) ar[rg] = alphaL[w * 16 + quad * 4 + rg];
#pragma unroll
    for (int nf = 0; nf < 8; nf++)
#pragma unroll
      for (int rg = 0; rg < 4; rg++) of[nf][rg] *= ar[rg];
#pragma unroll
    for (int ks = 0; ks < 2; ks++) {
      short8 pa = *(const short8*)((u16*)SP + (w * 16 + l15) * 136 + ks * 32 + quad * 8);
#pragma unroll
      for (int nf = 0; nf < 8; nf++) {
        short8 vb = *(const short8*)&Vt[(nf * 16 + l15) * 72 + ks * 32 + quad * 8];
        of[nf] = mfma16(pa, vb, of[nf]);
      }
    }
  }
  __syncthreads();
  float linv[4];
#pragma unroll
  for (int rg = 0; rg < 4; rg++) linv[rg] = 1.f / lstate[w * 16 + quad * 4 + rg];
  const int b = bh >> 4, h = bh & 15;
#pragma unroll
  for (int nf = 0; nf < 8; nf++)
#pragma unroll
    for (int rg = 0; rg < 4; rg++) {
      int tt = q0 + w * 16 + quad * 4 + rg;
      attno[((size_t)(b * 2048 + tt)) * 2048 + h * 128 + nf * 16 + l15] =
          f2bf(of[nf][rg] * linv[rg]);
    }
}

extern "C" void kernel_launch(void* const* d_in, const int* in_sizes, int n_in,
                              void* d_out, int out_size, void* d_ws, size_t ws_size,
                              hipStream_t stream) {
  const float* x = (const float*)d_in[0];
  const float* Wqkv = (const float*)d_in[1];
  const float* Wout = (const float*)d_in[2];
  const float* cosT = (const float*)d_in[3];
  const float* sinT = (const float*)d_in[4];
  float* out = (float*)d_out;
  char* ws = (char*)d_ws;
  // workspace layout (bytes), 96 MiB total, with lifetime-based reuse:
  //   [0,          50331648)  qkvh  (q|k|v head-major bf16, persists gemm1->attn)
  //   [50331648,   58720256)  woutb (persists to gemm2)
  //   [58720256,   75497472)  xb    (until gemm1)  -> reused as vT (transpose->attn)
  //   [75497472,  100663296)  wqkvb (until gemm1)  -> first 16MB reused as attno
  u16* qkvh = (u16*)(ws + 0);
  u16* woutb = (u16*)(ws + 50331648);
  u16* xb = (u16*)(ws + 58720256);
  u16* wqkvb = (u16*)(ws + 75497472);
  u16* vT = xb;
  u16* attno = wqkvb;

  cvt_bf16<<<4096, 256, 0, stream>>>(x, xb, 8388608);
  cvt_bf16<<<6144, 256, 0, stream>>>(Wqkv, wqkvb, 12582912);
  cvt_bf16<<<2048, 256, 0, stream>>>(Wout, woutb, 4194304);
  gemm_bt<0><<<dim3(48, 32), 256, 0, stream>>>(xb, wqkvb, 2048, (void*)qkvh, 0);
  rope_k<<<8192, 256, 0, stream>>>(qkvh, qkvh + 8388608, cosT, sinT);
  transpose_v<<<dim3(32, 2, 32), 256, 0, stream>>>(qkvh + 16777216, vT);
  attn_k<<<dim3(32, 32), 256, 0, stream>>>(qkvh, qkvh + 8388608, vT, attno);
  gemm_bt<1><<<dim3(16, 32), 256, 0, stream>>>(attno, woutb, 2048, (void*)out, 2048);
}

// Round 4
// 418.688 us; speedup vs baseline: 1.2017x; 1.2017x over previous
//
#include <hip/hip_runtime.h>
#include <stdint.h>

typedef unsigned short u16;
typedef __attribute__((ext_vector_type(8))) short short8;
typedef __attribute__((ext_vector_type(4))) short s16x4;
typedef __attribute__((ext_vector_type(4))) float f32x4;

__device__ __forceinline__ u16 f2bf(float f) {
  uint32_t x = __float_as_uint(f);
  x += 0x7fff + ((x >> 16) & 1);
  return (u16)(x >> 16);
}
__device__ __forceinline__ float bf2f(u16 u) {
  return __uint_as_float(((uint32_t)u) << 16);
}
__device__ __forceinline__ f32x4 mfma16(short8 a, short8 b, f32x4 c) {
  return __builtin_amdgcn_mfma_f32_16x16x32_bf16(a, b, c, 0, 0, 0);
}
__device__ __forceinline__ f32x4 mfma16k16(s16x4 a, s16x4 b, f32x4 c) {
  return __builtin_amdgcn_mfma_f32_16x16x16bf16_1k(a, b, c, 0, 0, 0);
}
__device__ __forceinline__ void gld16(const u16* g, u16* l) {
  __builtin_amdgcn_global_load_lds(
      (const __attribute__((address_space(1))) unsigned int*)g,
      (__attribute__((address_space(3))) unsigned int*)l, 16, 0, 0);
}
__device__ __forceinline__ float exp2a(float x) {  // raw v_exp_f32 (2^x)
  float r;
  asm("v_exp_f32 %0, %1" : "=v"(r) : "v"(x));
  return r;
}

// ---------------- fused fp32 -> bf16 conversion (x | Wqkv | Wout) ----------------
__global__ __launch_bounds__(256) void cvt_all(const float* __restrict__ x,
                                               const float* __restrict__ wqkv,
                                               const float* __restrict__ wout,
                                               u16* __restrict__ xb,
                                               u16* __restrict__ wqkvb,
                                               u16* __restrict__ woutb) {
  long i = ((long)blockIdx.x * 256 + threadIdx.x) * 8;
  const float* s;
  u16* d;
  long off;
  if (i < 8388608) {
    s = x; d = xb; off = i;
  } else if (i < 20971520) {
    s = wqkv; d = wqkvb; off = i - 8388608;
  } else {
    s = wout; d = woutb; off = i - 20971520;
  }
  f32x4 a = *(const f32x4*)(s + off);
  f32x4 b = *(const f32x4*)(s + off + 4);
  short8 o;
#pragma unroll
  for (int j = 0; j < 4; j++) {
    o[j] = (short)f2bf(a[j]);
    o[j + 4] = (short)f2bf(b[j]);
  }
  *(short8*)(d + off) = o;
}

// ---------------- m97-style BT GEMM: C = A(MxK) * B(NxK)^T ----------------
// EPI=0: scatter bf16: q (pre-scaled by 1/sqrt(128)*log2e), k head-major
//        [B,H,T,128]; v written TRANSPOSED per head [B,H,128,T].
// EPI=1: fp32 row-major MxN
template <int EPI>
__global__ __launch_bounds__(256) void gemm_bt(const u16* __restrict__ A,
                                               const u16* __restrict__ B,
                                               int K, void* __restrict__ Cv, int N) {
  __shared__ __align__(16) u16 As[4096];  // 128 x 32
  __shared__ __align__(16) u16 Bs[4096];  // 128 x 32
  const int m0 = blockIdx.y * 128, n0 = blockIdx.x * 128;
  const int t = threadIdx.x, w = t >> 6, lane = t & 63;
  const int quad = lane >> 4, l15 = lane & 15;
  const int rb = (w >> 1) * 64, cb = (w & 1) * 64;
  f32x4 acc[4][4] = {};
  const u16* ag = A + (size_t)(m0 + w * 16 + (lane >> 2)) * K + (lane & 3) * 8;
  const u16* bg = B + (size_t)(n0 + w * 16 + (lane >> 2)) * K + (lane & 3) * 8;
  u16* al = As + w * 512 + lane * 8;  // lane-contiguous: base + lane*16B
  u16* bl = Bs + w * 512 + lane * 8;
  const size_t rowskip = (size_t)64 * K;
  for (int k0 = 0; k0 < K; k0 += 32) {
    __syncthreads();
    gld16(ag, al);
    gld16(ag + rowskip, al + 2048);
    gld16(bg, bl);
    gld16(bg + rowskip, bl + 2048);
    ag += 32;
    bg += 32;
    __syncthreads();
    short8 af[4], bfr[4];
#pragma unroll
    for (int mf = 0; mf < 4; mf++)
      af[mf] = *(const short8*)&As[(rb + mf * 16 + l15) * 32 + quad * 8];
#pragma unroll
    for (int nf = 0; nf < 4; nf++)
      bfr[nf] = *(const short8*)&Bs[(cb + nf * 16 + l15) * 32 + quad * 8];
#pragma unroll
    for (int mf = 0; mf < 4; mf++)
#pragma unroll
      for (int nf = 0; nf < 4; nf++)
        acc[mf][nf] = mfma16(af[mf], bfr[nf], acc[mf][nf]);
  }
  if (EPI == 0) {
    u16* q3 = (u16*)Cv;
    const int which = n0 >> 11;  // uniform per block (n0 tile-aligned)
    if (which == 2) {
      // v transposed: vT[bh][d][t], 4 consecutive t per lane -> 8B store
#pragma unroll
      for (int mf = 0; mf < 4; mf++)
#pragma unroll
        for (int nf = 0; nf < 4; nf++) {
          int m = m0 + rb + mf * 16 + quad * 4;
          int n = n0 + cb + nf * 16 + l15;
          int dd = n & 2047, hh = dd >> 7, di = dd & 127;
          int bb = m >> 11, tt = m & 2047;
          s16x4 st;
#pragma unroll
          for (int rg = 0; rg < 4; rg++) st[rg] = (short)f2bf(acc[mf][nf][rg]);
          *(s16x4*)(q3 + 16777216 + ((size_t)(bb * 16 + hh) * 128 + di) * 2048 + tt) = st;
        }
    } else {
      const float sc = (which == 0) ? 0.1275174f : 1.0f;  // 1/sqrt(128)*log2(e)
      u16* base = q3 + (size_t)which * 8388608;
#pragma unroll
      for (int mf = 0; mf < 4; mf++)
#pragma unroll
        for (int nf = 0; nf < 4; nf++) {
          int m = m0 + rb + mf * 16 + quad * 4;
          int n = n0 + cb + nf * 16 + l15;
          int dd = n & 2047, hh = dd >> 7, di = dd & 127;
          int bb = m >> 11, tt = m & 2047;
#pragma unroll
          for (int rg = 0; rg < 4; rg++)
            base[((size_t)(bb * 16 + hh) * 2048 + tt + rg) * 128 + di] =
                f2bf(acc[mf][nf][rg] * sc);
        }
    }
  } else {
    float* C = (float*)Cv;
#pragma unroll
    for (int mf = 0; mf < 4; mf++)
#pragma unroll
      for (int nf = 0; nf < 4; nf++)
#pragma unroll
        for (int rg = 0; rg < 4; rg++) {
          int m = m0 + rb + mf * 16 + quad * 4 + rg;
          int n = n0 + cb + nf * 16 + l15;
          C[(size_t)m * N + n] = acc[mf][nf][rg];
        }
  }
}

// ---------------- RoPE in-place on q,k (heads 0..7 only) ----------------
__global__ __launch_bounds__(256) void rope_k(u16* __restrict__ q, u16* __restrict__ k,
                                              const float* __restrict__ cosT,
                                              const float* __restrict__ sinT) {
  int t = threadIdx.x;
  int row = blockIdx.x * 4 + (t >> 6);  // over (b, h<8, tpos)
  int i = t & 63;
  int b = row >> 14;
  int h = (row >> 11) & 7;
  int tp = row & 2047;
  size_t base = ((size_t)((b * 16 + h) * 2048 + tp)) * 128 + 2 * i;
  float c = cosT[tp * 64 + i], s = sinT[tp * 64 + i];
  {
    uint32_t u = *(uint32_t*)(q + base);
    float x0 = bf2f((u16)(u & 0xffff)), x1 = bf2f((u16)(u >> 16));
    float re = x0 * c - x1 * s, im = x0 * s + x1 * c;
    *(uint32_t*)(q + base) = (uint32_t)f2bf(re) | ((uint32_t)f2bf(im) << 16);
  }
  {
    uint32_t u = *(uint32_t*)(k + base);
    float x0 = bf2f((u16)(u & 0xffff)), x1 = bf2f((u16)(u >> 16));
    float re = x0 * c - x1 * s, im = x0 * s + x1 * c;
    *(uint32_t*)(k + base) = (uint32_t)f2bf(re) | ((uint32_t)f2bf(im) << 16);
  }
}

// ---------------- flash attention, S^T orientation ----------------
// Q-tile 128 (4 waves x 32 q), K-tile 64. In-register online softmax
// (in-lane + shfl_xor 16/32). P^T in C-layout feeds 16x16x16 PV MFMA
// directly (B-frag == lane's own values) -> no P LDS round trip.
// 2 barriers per tile. Scores already scaled by 1/sqrt(128)*log2e -> exp2.
__global__ __launch_bounds__(256, 2) void attn_k(const u16* __restrict__ qh,
                                                 const u16* __restrict__ kh,
                                                 const u16* __restrict__ vTh,
                                                 u16* __restrict__ attno) {
  __shared__ __align__(16) u16 Ks[8192];  // 64 keys x 128 d, XOR-swizzled 16B chunks
  __shared__ __align__(16) u16 Vt[8192];  // 128 d x 64 keys, XOR-swizzled 16B chunks
  // block index -> (bh, qt): blocks i and i+256 land on the same CU
  // (XCD round-robin heuristic); their qt's are complementary so paired
  // work is constant (34 K-tiles).
  const int i = blockIdx.x;
  const int jj = i & 255, half = i >> 8;
  const int bh = jj >> 3, t8 = jj & 7;
  const int qt = half ? (15 - t8) : t8;
  const int q0 = qt * 128;
  const int t = threadIdx.x, w = t >> 6, lane = t & 63;
  const int quad = lane >> 4, l15 = lane & 15;
  const size_t bhoff = (size_t)bh * 262144;

  // Q B-frags in registers: Q[q=wq0+qq*16+l15][d=ks*32+quad*8+j]
  short8 qb[2][4];
  {
    const u16* qp = qh + bhoff + (size_t)(q0 + w * 32 + l15) * 128 + quad * 8;
#pragma unroll
    for (int qq = 0; qq < 2; qq++)
#pragma unroll
      for (int ks = 0; ks < 4; ks++)
        qb[qq][ks] = *(const short8*)(qp + qq * 2048 + ks * 32);
  }
  f32x4 of[2][8] = {};  // O^T[d=df*16+quad*4+rg][q=wq0+qq*16+l15]
  float mst[2] = {-1e30f, -1e30f}, lst[2] = {0.f, 0.f};
  const int nkt = 2 * qt + 2;
  const int wq0 = q0 + w * 32;

  for (int kt = 0; kt < nkt; kt++) {
    const int k0 = kt * 64;
    __syncthreads();  // all waves done reading previous K/V
    {
#pragma unroll
      for (int it = 0; it < 4; it++) {  // K: 64 rows x 16 chunks
        int L = it * 256 + t;
        int key = L >> 4, c = L & 15;
        gld16(kh + bhoff + (size_t)(k0 + key) * 128 + ((c ^ (key & 15)) * 8),
              Ks + (size_t)L * 8);
      }
#pragma unroll
      for (int it = 0; it < 4; it++) {  // V^T: 128 rows x 8 chunks
        int L = it * 256 + t;
        int d = L >> 3, c = L & 7;
        gld16(vTh + bhoff + (size_t)d * 2048 + k0 + ((c ^ (d & 7)) * 8),
              Vt + (size_t)L * 8);
      }
    }
    __syncthreads();  // staging visible
    if (k0 <= wq0 + 31) {  // wave has at least one unmasked key
      // S^T = K * Q^T : C[key=kk*16+quad*4+rg][q=wq0+qq*16+l15]
      f32x4 sacc[2][4];
#pragma unroll
      for (int qq = 0; qq < 2; qq++)
#pragma unroll
        for (int kk = 0; kk < 4; kk++) sacc[qq][kk] = (f32x4){0.f, 0.f, 0.f, 0.f};
#pragma unroll
      for (int kk = 0; kk < 4; kk++) {
        short8 kf[4];
#pragma unroll
        for (int ks = 0; ks < 4; ks++)
          kf[ks] = *(const short8*)&Ks[(kk * 16 + l15) * 128 + ((ks * 4 + quad) ^ l15) * 8];
#pragma unroll
        for (int qq = 0; qq < 2; qq++)
#pragma unroll
          for (int ks = 0; ks < 4; ks++)
            sacc[qq][kk] = mfma16(kf[ks], qb[qq][ks], sacc[qq][kk]);
      }
      const bool needmask = (k0 + 63 > wq0);
      s16x4 pf[2][4];
      float alpha[2];
#pragma unroll
      for (int qq = 0; qq < 2; qq++) {
        const int qg = wq0 + qq * 16 + l15;
        if (needmask) {
#pragma unroll
          for (int kk = 0; kk < 4; kk++)
#pragma unroll
            for (int rg = 0; rg < 4; rg++)
              if (k0 + kk * 16 + quad * 4 + rg > qg) sacc[qq][kk][rg] = -1e30f;
        }
        float pm = -1e30f;
#pragma unroll
        for (int kk = 0; kk < 4; kk++)
#pragma unroll
          for (int rg = 0; rg < 4; rg++) pm = fmaxf(pm, sacc[qq][kk][rg]);
        pm = fmaxf(pm, __shfl_xor(pm, 16));
        pm = fmaxf(pm, __shfl_xor(pm, 32));
        float mnew = fmaxf(mst[qq], pm);
        alpha[qq] = exp2a(mst[qq] - mnew);
        mst[qq] = mnew;
        float ps = 0.f;
#pragma unroll
        for (int kk = 0; kk < 4; kk++) {
          float e0 = exp2a(sacc[qq][kk][0] - mnew);
          float e1 = exp2a(sacc[qq][kk][1] - mnew);
          float e2 = exp2a(sacc[qq][kk][2] - mnew);
          float e3 = exp2a(sacc[qq][kk][3] - mnew);
          ps += (e0 + e1) + (e2 + e3);
          pf[qq][kk][0] = (short)f2bf(e0);
          pf[qq][kk][1] = (short)f2bf(e1);
          pf[qq][kk][2] = (short)f2bf(e2);
          pf[qq][kk][3] = (short)f2bf(e3);
        }
        ps += __shfl_xor(ps, 16);
        ps += __shfl_xor(ps, 32);
        lst[qq] = lst[qq] * alpha[qq] + ps;
      }
#pragma unroll
      for (int qq = 0; qq < 2; qq++) {
        if (!__all(alpha[qq] == 1.0f)) {
          float a = alpha[qq];
#pragma unroll
          for (int df = 0; df < 8; df++) of[qq][df] *= a;
        }
      }
      // O^T += V^T * P^T (16x16x16): A from Vt LDS, B = lane's own pf
#pragma unroll
      for (int df = 0; df < 8; df++) {
        s16x4 vf[4];
#pragma unroll
        for (int kk = 0; kk < 4; kk++)
          vf[kk] = *(const s16x4*)&Vt[(df * 16 + l15) * 64 +
                                      ((kk * 2 + (quad >> 1)) ^ (l15 & 7)) * 8 +
                                      (quad & 1) * 4];
#pragma unroll
        for (int qq = 0; qq < 2; qq++)
#pragma unroll
          for (int kk = 0; kk < 4; kk++)
            of[qq][df] = mfma16k16(vf[kk], pf[qq][kk], of[qq][df]);
      }
    }
  }
  // epilogue: O[q][h*128+d], 4 consecutive d per lane -> 8B stores
  const int b = bh >> 4, h = bh & 15;
#pragma unroll
  for (int qq = 0; qq < 2; qq++) {
    float linv = 1.0f / lst[qq];
    const size_t row = (size_t)(b * 2048 + q0 + w * 32 + qq * 16 + l15);
#pragma unroll
    for (int df = 0; df < 8; df++) {
      s16x4 o;
#pragma unroll
      for (int rg = 0; rg < 4; rg++) o[rg] = (short)f2bf(of[qq][df][rg] * linv);
      *(s16x4*)(attno + row * 2048 + h * 128 + df * 16 + quad * 4) = o;
    }
  }
}

extern "C" void kernel_launch(void* const* d_in, const int* in_sizes, int n_in,
                              void* d_out, int out_size, void* d_ws, size_t ws_size,
                              hipStream_t stream) {
  const float* x = (const float*)d_in[0];
  const float* Wqkv = (const float*)d_in[1];
  const float* Wout = (const float*)d_in[2];
  const float* cosT = (const float*)d_in[3];
  const float* sinT = (const float*)d_in[4];
  float* out = (float*)d_out;
  char* ws = (char*)d_ws;
  // workspace (96 MiB), lifetime-based reuse:
  //   [0,        50331648)  qkvh: q | k | vT (vT = per-head transposed v)
  //   [50331648, 58720256)  woutb (persists to gemm2)
  //   [58720256, 75497472)  xb (dead after gemm1)
  //   [75497472,100663296)  wqkvb (dead after gemm1) -> reused as attno
  u16* qkvh = (u16*)(ws + 0);
  u16* woutb = (u16*)(ws + 50331648);
  u16* xb = (u16*)(ws + 58720256);
  u16* wqkvb = (u16*)(ws + 75497472);
  u16* attno = wqkvb;

  cvt_all<<<12288, 256, 0, stream>>>(x, Wqkv, Wout, xb, wqkvb, woutb);
  gemm_bt<0><<<dim3(48, 32), 256, 0, stream>>>(xb, wqkvb, 2048, (void*)qkvh, 0);
  rope_k<<<8192, 256, 0, stream>>>(qkvh, qkvh + 8388608, cosT, sinT);
  attn_k<<<512, 256, 0, stream>>>(qkvh, qkvh + 8388608, qkvh + 16777216, attno);
  gemm_bt<1><<<dim3(16, 32), 256, 0, stream>>>(attno, woutb, 2048, (void*)out, 2048);
}